// Round 11
// baseline (2261.597 us; speedup 1.0000x reference)
//
#include <hip/hip_runtime.h>
#include <stdint.h>

// CondDecoder: B=256, T=128, V=64, L=128, H=512, E=32, NL=3, IN0=161 (pad 192)
// All inter-layer activations are (t,b)-major: row m = t*256 + b. This lets the
// GRU h-exchange publish double as the next GEMM's A matrix (no xo stores).
#define TT 128
#define G3 1536

typedef __attribute__((ext_vector_type(8))) short bf16x8;
typedef __attribute__((ext_vector_type(4))) float f32x4;

__device__ __forceinline__ unsigned short f2bf(float f){
  unsigned int x = __builtin_bit_cast(unsigned int, f);
  x = x + 0x7fffu + ((x >> 16) & 1u);
  return (unsigned short)(x >> 16);
}
__device__ __forceinline__ float bf2f(unsigned short u){
  unsigned int x = ((unsigned int)u) << 16;
  return __builtin_bit_cast(float, x);
}
__device__ __forceinline__ void gl_lds16(const void* g, void* l){
  __builtin_amdgcn_global_load_lds((const __attribute__((address_space(1))) unsigned int*)g,
                                   (__attribute__((address_space(3))) unsigned int*)l, 16, 0, 0);
}

// ---- prep: Wih1, Wih2 f32 -> bf16 flat
__global__ __launch_bounds__(256) void kconv2(const float* __restrict__ a0,
    const float* __restrict__ a1, unsigned short* __restrict__ d0,
    unsigned short* __restrict__ d1){
  int i = blockIdx.x*256 + threadIdx.x;   // grid 3072*256 = 786432
  d0[i] = f2bf(a0[i]); d1[i] = f2bf(a1[i]);
}

// ---- prep: Whh -> fragment-permuted bf16 so kgru weight loads are coalesced.
// dst i = (((wblk*3+g)*16+ks)*64+lane)*8+e ; wblk=cb*8+w owns cols wblk*16..+15
__global__ __launch_bounds__(256) void kwperm(const float* __restrict__ wsrc,
    unsigned short* __restrict__ o){
  int i = blockIdx.x*256 + threadIdx.x;   // grid 3072
  int e = i & 7, lane = (i >> 3) & 63, ks = (i >> 9) & 15, rem = i >> 13;
  int g = rem % 3, wblk = rem / 3;
  int gcol = wblk*16 + (lane & 15);
  int k = ks*32 + (lane >> 4)*8 + e;
  o[i] = f2bf(wsrc[(size_t)(g*512 + gcol)*512 + k]);
}

// ---- prep: Wih0 pad 161->192 to bf16; fc_W transpose to [512][64] f32
__global__ __launch_bounds__(256) void kmisc(const float* __restrict__ wih0,
    unsigned short* __restrict__ wih0p, const float* __restrict__ fcw,
    float* __restrict__ fcwt){
  int i = blockIdx.x*256 + threadIdx.x;  // grid 1152
  if (i < 1536*192){
    int n = i / 192, k = i - n*192;
    wih0p[i] = (k < 161) ? f2bf(wih0[n*161 + k]) : (unsigned short)0;
  }
  if (i < 512*64){
    int k = i >> 6, v = i & 63;
    fcwt[i] = fcw[v*512 + k];
  }
}

// ---- prep: build x0 [32768][192] bf16 in (t,b) order: m = t*256 + b
__global__ __launch_bounds__(192) void kx0(const float* __restrict__ latent,
    const float* __restrict__ enth, const int* __restrict__ inp,
    const float* __restrict__ emb, unsigned short* __restrict__ x0){
  int c = threadIdx.x;
  #pragma unroll
  for (int mr = 0; mr < 4; ++mr){
    int m = blockIdx.x*4 + mr;       // grid 8192
    int b = m & 255, t = m >> 8;
    float v;
    if (c < 128) v = latent[b*128 + c];
    else if (c < 160){
      int tok = (t == 0) ? 0 : inp[b*128 + t - 1];
      v = emb[tok*32 + (c - 128)];
    }
    else if (c == 160) v = enth[b];
    else v = 0.f;
    x0[(size_t)m*192 + c] = f2bf(v);
  }
}

// ---- bf16 MFMA GEMM (row-order-blind): C[m][n] = A[m][K] @ Bt[n][K]^T + bias[n]
__global__ __launch_bounds__(256) void kgemm(const unsigned short* __restrict__ A,
    const unsigned short* __restrict__ Bt, const float* __restrict__ bias,
    unsigned short* __restrict__ C, int K){
  __shared__ __align__(16) unsigned short As[128*32];
  __shared__ __align__(16) unsigned short Bs[128*32];
  const int m0 = blockIdx.y*128, n0 = blockIdx.x*128;
  const int wv = threadIdx.x >> 6, lane = threadIdx.x & 63;
  const int woffM = (wv >> 1)*64, woffN = (wv & 1)*64;
  f32x4 acc[4][4] = {};
  for (int k0 = 0; k0 < K; k0 += 32){
    __syncthreads();
    #pragma unroll
    for (int i = 0; i < 4; ++i){
      int e = wv*4 + i;
      int ee = e & 7;
      int row = ee*16 + (lane >> 2);
      if (e < 8) gl_lds16(A  + (size_t)(m0+row)*K + k0 + (lane & 3)*8, (void*)&As[ee*512]);
      else       gl_lds16(Bt + (size_t)(n0+row)*K + k0 + (lane & 3)*8, (void*)&Bs[ee*512]);
    }
    __syncthreads();
    bf16x8 af[4], bf_[4];
    #pragma unroll
    for (int mt = 0; mt < 4; ++mt)
      af[mt] = *(const bf16x8*)&As[(woffM + mt*16 + (lane & 15))*32 + (lane >> 4)*8];
    #pragma unroll
    for (int nt = 0; nt < 4; ++nt)
      bf_[nt] = *(const bf16x8*)&Bs[(woffN + nt*16 + (lane & 15))*32 + (lane >> 4)*8];
    #pragma unroll
    for (int mt = 0; mt < 4; ++mt)
      #pragma unroll
      for (int nt = 0; nt < 4; ++nt)
        acc[mt][nt] = __builtin_amdgcn_mfma_f32_16x16x32_bf16(af[mt], bf_[nt], acc[mt][nt], 0, 0, 0);
  }
  const int col = lane & 15, lq = lane >> 4;
  #pragma unroll
  for (int nt = 0; nt < 4; ++nt){
    float bv = bias[n0 + woffN + nt*16 + col];
    #pragma unroll
    for (int mt = 0; mt < 4; ++mt)
      #pragma unroll
      for (int r = 0; r < 4; ++r){
        int grow = m0 + woffM + mt*16 + lq*4 + r;
        int gcol = n0 + woffN + nt*16 + col;
        C[(size_t)grow*G3 + gcol] = f2bf(acc[mt][nt][r] + bv);
      }
  }
}

// ---- GRU layer: 64 blocks = 16 rowgroups(16 rows) x 4 colblocks(128 cols x 3 gates).
// 512 threads / 8 waves. Whh slice PINNED in VGPRs (192/lane) via opaque asm —
// R10's VGPR_Count=128 showed the compiler re-loading weights from L2 every step.
// h exchange via proven MALL protocol (atomics only; sc0/sc1 asm failed R5/R9).
// hist[t][B][512] is publish target AND next-GEMM A matrix (no separate xo stores;
// no double-buffer WAR — each t owns a slot). Per-wave flags; 1 barrier/step.
template<int STORE_F>
__global__ __launch_bounds__(512, 2) void kgru(
    const unsigned short* __restrict__ Wp, const float* __restrict__ bhh,
    const unsigned short* __restrict__ gi,
    unsigned short* __restrict__ hist, float* __restrict__ x2f,
    int* __restrict__ flags){
  const int bid = blockIdx.x;
  const int rg = bid & 15, cb = bid >> 4;
  const int b0 = rg*16;
  const int tid = threadIdx.x;
  const int w = tid >> 6, lane = tid & 63;
  const int c = lane & 15, lq = lane >> 4;
  const int gcol = cb*128 + w*16 + c;
  __shared__ __align__(16) unsigned short hs[2][16*512];   // 32KB staging (dbuf)
  __shared__ __align__(16) unsigned short hpub[8][256];    // 4KB bf16 publish shuffle
  __shared__ __align__(16) float hpf[8][256];              // 8KB f32 shuffle (final layer)

  // resident Whh fragments (coalesced; pre-permuted): 192 VGPR, PINNED
  const unsigned short* wbase = Wp + (size_t)(cb*8 + w)*24576 + lane*8;
  bf16x8 wf[3][16];
  #pragma unroll
  for (int g = 0; g < 3; ++g)
    #pragma unroll
    for (int ks = 0; ks < 16; ++ks)
      wf[g][ks] = *(const bf16x8*)(wbase + g*8192 + ks*512);
  #pragma unroll
  for (int g = 0; g < 3; ++g)
    #pragma unroll
    for (int ks = 0; ks < 16; ++ks)
      asm volatile("" : "+v"(wf[g][ks]));    // opaque def: loads cannot be re-sunk
  float bias[3];
  #pragma unroll
  for (int g = 0; g < 3; ++g) bias[g] = bhh[g*512 + gcol];
  float h_old[4] = {0.f, 0.f, 0.f, 0.f};

  unsigned long long* hist8 = (unsigned long long*)hist;
  int* myf = flags + rg*32;                      // 32 per-wave slots (cb*8+w)
  const unsigned short* gp = gi + (size_t)(b0 + lq*4)*G3 + gcol;

  #pragma unroll 1
  for (int t = 0; t < TT; ++t){
    // gate-input loads (latency hidden under poll/pull)
    f32x4 acc[3]; f32x4 gin;
    #pragma unroll
    for (int r = 0; r < 4; ++r){
      const unsigned short* p = gp + (size_t)r*G3;
      acc[0][r] = bf2f(p[0])    + bias[0];
      acc[1][r] = bf2f(p[512])  + bias[1];
      acc[2][r] = bias[2];
      gin[r]    = bf2f(p[1024]);
    }
    gp += (size_t)256*G3;
    if (t > 0){
      // poll the 32 per-wave flags of this rowgroup
      while (true){
        int f = __hip_atomic_load(myf + (lane & 31), __ATOMIC_RELAXED, __HIP_MEMORY_SCOPE_AGENT);
        if (__all(f >= t)) break;
        __builtin_amdgcn_s_sleep(1);
      }
      // pull 16KB of h_{t-1} (2048 qwords, 4/thread) -> swizzled LDS
      const unsigned long long* src8 = hist8 + ((size_t)(t - 1)*256 + b0)*128;
      unsigned long long pv[4];
      #pragma unroll
      for (int j = 0; j < 4; ++j)
        pv[j] = __hip_atomic_load(src8 + tid + j*512, __ATOMIC_RELAXED, __HIP_MEMORY_SCOPE_AGENT);
      char* hsw = (char*)hs[t & 1];
      #pragma unroll
      for (int j = 0; j < 4; ++j){
        int idx = tid + j*512;
        int row = idx >> 7, q = idx & 127;
        *(unsigned long long*)(hsw + row*1024 + (((q >> 1) ^ (row & 7)) << 4)
                               + ((q & 1) << 3)) = pv[j];
      }
    }
    __syncthreads();                               // one barrier per step
    if (t > 0){
      const char* hsr = (const char*)hs[t & 1];
      #pragma unroll
      for (int ks = 0; ks < 16; ++ks){
        bf16x8 af = *(const bf16x8*)(hsr + c*1024 + (((ks*4 + lq) ^ (c & 7)) << 4));
        acc[0] = __builtin_amdgcn_mfma_f32_16x16x32_bf16(af, wf[0][ks], acc[0], 0, 0, 0);
        acc[1] = __builtin_amdgcn_mfma_f32_16x16x32_bf16(af, wf[1][ks], acc[1], 0, 0, 0);
        acc[2] = __builtin_amdgcn_mfma_f32_16x16x32_bf16(af, wf[2][ks], acc[2], 0, 0, 0);
      }
    }
    // gates (fully in-lane)
    unsigned short hv[4]; float hf[4];
    #pragma unroll
    for (int r = 0; r < 4; ++r){
      float rr = 1.f/(1.f + __expf(-acc[0][r]));
      float zz = 1.f/(1.f + __expf(-acc[1][r]));
      float np = gin[r] + rr*acc[2][r];
      float ee = __expf(2.f*np);
      float nn = 1.f - 2.f/(ee + 1.f);
      float hn = (1.f - zz)*nn + zz*h_old[r];
      h_old[r] = hn; hf[r] = hn; hv[r] = f2bf(hn);
    }
    // wave-local publish shuffle (16 rows x 16 cols per wave)
    #pragma unroll
    for (int r = 0; r < 4; ++r)
      hpub[w][(lq*4 + r)*16 + c] = hv[r];
    if (STORE_F){
      #pragma unroll
      for (int r = 0; r < 4; ++r)
        hpf[w][(lq*4 + r)*16 + c] = hf[r];
    }
    __builtin_amdgcn_sched_barrier(0);
    // 1 qword/lane, coalesced: publish h_t into hist (exchange + next-GEMM A)
    unsigned long long pub = *(const unsigned long long*)&hpub[w][(lane >> 2)*16 + (lane & 3)*4];
    unsigned long long* dst8 = hist8 + ((size_t)t*256 + b0)*128;
    __hip_atomic_store(dst8 + (lane >> 2)*128 + cb*32 + w*4 + (lane & 3), pub,
                       __ATOMIC_RELAXED, __HIP_MEMORY_SCOPE_AGENT);
    asm volatile("s_waitcnt vmcnt(0)" ::: "memory");   // this wave's h at MALL
    if (lane == 0)
      __hip_atomic_store(myf + (cb*8 + w), t + 1, __ATOMIC_RELAXED, __HIP_MEMORY_SCOPE_AGENT);
    __builtin_amdgcn_sched_barrier(0);                 // f32 stream strictly after flag
    if (STORE_F){
      const float* pf = &hpf[w][(lane >> 2)*16 + (lane & 3)*4];
      unsigned long long f0 = ((const unsigned long long*)pf)[0];
      unsigned long long f1 = ((const unsigned long long*)pf)[1];
      unsigned long long* xd = (unsigned long long*)x2f
          + ((size_t)t*256 + b0 + (lane >> 2))*256 + cb*64 + w*8 + (lane & 3)*2;
      xd[0] = f0; xd[1] = f1;
    }
  }
}

// ---- final FC in f32: logits[b][t][64] = x[(t,b)][512] @ fcwt + fc_b
__global__ __launch_bounds__(256) void kfc(const float* __restrict__ x,
    const float* __restrict__ wt, const float* __restrict__ fcb, float* __restrict__ out){
  __shared__ __align__(16) float xs[16*512];
  const int m0 = blockIdx.x*16;   // grid 2048; 16 rows share t (16 | 256)
  for (int c = threadIdx.x; c < 2048; c += 256){
    int row = c >> 7, o = c & 127;
    *(f32x4*)&xs[row*512 + o*4] = *(const f32x4*)(x + (size_t)(m0+row)*512 + o*4);
  }
  __syncthreads();
  const int colv = threadIdx.x & 63, rq = threadIdx.x >> 6;
  float a0 = 0.f, a1 = 0.f, a2 = 0.f, a3 = 0.f;
  const float* x0p = xs + (rq*4 + 0)*512;
  const float* x1p = xs + (rq*4 + 1)*512;
  const float* x2p = xs + (rq*4 + 2)*512;
  const float* x3p = xs + (rq*4 + 3)*512;
  #pragma unroll 8
  for (int k = 0; k < 512; ++k){
    float w = wt[k*64 + colv];
    a0 += w * x0p[k]; a1 += w * x1p[k]; a2 += w * x2p[k]; a3 += w * x3p[k];
  }
  float bv = fcb[colv];
  float av[4] = {a0, a1, a2, a3};
  #pragma unroll
  for (int j = 0; j < 4; ++j){
    int m = m0 + rq*4 + j;
    int b = m & 255, t = m >> 8;               // (t,b) -> [b][t][64] output
    out[((size_t)b*128 + t)*64 + colv] = av[j] + bv;
  }
}

extern "C" void kernel_launch(void* const* d_in, const int* in_sizes, int n_in,
                              void* d_out, int out_size, void* d_ws, size_t ws_size,
                              hipStream_t stream){
  const float* latent = (const float*)d_in[0];
  const float* enth   = (const float*)d_in[1];
  const int*   inp    = (const int*)d_in[2];
  const float* emb    = (const float*)d_in[3];
  const float* Wih0   = (const float*)d_in[4];
  const float* Whh0   = (const float*)d_in[5];
  const float* bih0   = (const float*)d_in[6];
  const float* bhh0   = (const float*)d_in[7];
  const float* Wih1   = (const float*)d_in[8];
  const float* Whh1   = (const float*)d_in[9];
  const float* bih1   = (const float*)d_in[10];
  const float* bhh1   = (const float*)d_in[11];
  const float* Wih2   = (const float*)d_in[12];
  const float* Whh2   = (const float*)d_in[13];
  const float* bih2   = (const float*)d_in[14];
  const float* bhh2   = (const float*)d_in[15];
  const float* fcW    = (const float*)d_in[16];
  const float* fcb    = (const float*)d_in[17];

  char* ws = (char*)d_ws;
  constexpr size_t OFF_HIST = 4096;                                  // flags at 0 (2KB)
  constexpr size_t OFF_X0   = OFF_HIST + (size_t)32768*512*2;        // 32MB hist
  constexpr size_t OFF_X2F  = OFF_X0   + (size_t)32768*192*2;
  constexpr size_t OFF_WHP  = OFF_X2F  + (size_t)32768*512*4;
  constexpr size_t OFF_WIH0 = OFF_WHP  + (size_t)3*1536*512*2;
  constexpr size_t OFF_WIH1 = OFF_WIH0 + (size_t)1536*192*2;
  constexpr size_t OFF_WIH2 = OFF_WIH1 + (size_t)1536*512*2;
  constexpr size_t OFF_FCWT = OFF_WIH2 + (size_t)1536*512*2;
  constexpr size_t OFF_GI   = OFF_FCWT + (size_t)512*64*4;

  int* flags            = (int*)ws;
  unsigned short* hist  = (unsigned short*)(ws + OFF_HIST);
  unsigned short* x0    = (unsigned short*)(ws + OFF_X0);
  float* x2f            = (float*)(ws + OFF_X2F);
  unsigned short* whp0  = (unsigned short*)(ws + OFF_WHP);
  unsigned short* whp1  = whp0 + (size_t)1536*512;
  unsigned short* whp2  = whp1 + (size_t)1536*512;
  unsigned short* wih0p = (unsigned short*)(ws + OFF_WIH0);
  unsigned short* wih1b = (unsigned short*)(ws + OFF_WIH1);
  unsigned short* wih2b = (unsigned short*)(ws + OFF_WIH2);
  float* fcwt           = (float*)(ws + OFF_FCWT);
  unsigned short* gi    = (unsigned short*)(ws + OFF_GI);

  kconv2<<<3072, 256, 0, stream>>>(Wih1, Wih2, wih1b, wih2b);
  kwperm<<<3072, 256, 0, stream>>>(Whh0, whp0);
  kwperm<<<3072, 256, 0, stream>>>(Whh1, whp1);
  kwperm<<<3072, 256, 0, stream>>>(Whh2, whp2);
  kmisc <<<1152, 256, 0, stream>>>(Wih0, wih0p, fcW, fcwt);
  kx0   <<<8192, 192, 0, stream>>>(latent, enth, inp, emb, x0);

  kgemm<<<dim3(12,256), 256, 0, stream>>>(x0, wih0p, bih0, gi, 192);
  (void)hipMemsetAsync(flags, 0, 2048, stream);
  kgru<0><<<64, 512, 0, stream>>>(whp0, bhh0, gi, hist, x2f, flags);
  kgemm<<<dim3(12,256), 256, 0, stream>>>(hist, wih1b, bih1, gi, 512);
  (void)hipMemsetAsync(flags, 0, 2048, stream);
  kgru<0><<<64, 512, 0, stream>>>(whp1, bhh1, gi, hist, x2f, flags);
  kgemm<<<dim3(12,256), 256, 0, stream>>>(hist, wih2b, bih2, gi, 512);
  (void)hipMemsetAsync(flags, 0, 2048, stream);
  kgru<1><<<64, 512, 0, stream>>>(whp2, bhh2, gi, hist, x2f, flags);
  kfc  <<<2048, 256, 0, stream>>>(x2f, fcwt, fcb, (float*)d_out);
}

// Round 12
// 1897.909 us; speedup vs baseline: 1.1916x; 1.1916x over previous
//
#include <hip/hip_runtime.h>
#include <stdint.h>

// CondDecoder: B=256, T=128, V=64, L=128, H=512, E=32, NL=3, IN0=161 (pad 192)
// All inter-layer activations are (t,b)-major: row m = t*256 + b. The GRU
// h-exchange publish doubles as the next GEMM's A matrix (no xo stores).
#define TT 128
#define G3 1536

typedef __attribute__((ext_vector_type(8))) short bf16x8;
typedef __attribute__((ext_vector_type(4))) float f32x4;

__device__ __forceinline__ unsigned short f2bf(float f){
  unsigned int x = __builtin_bit_cast(unsigned int, f);
  x = x + 0x7fffu + ((x >> 16) & 1u);
  return (unsigned short)(x >> 16);
}
__device__ __forceinline__ float bf2f(unsigned short u){
  unsigned int x = ((unsigned int)u) << 16;
  return __builtin_bit_cast(float, x);
}
__device__ __forceinline__ void gl_lds16(const void* g, void* l){
  __builtin_amdgcn_global_load_lds((const __attribute__((address_space(1))) unsigned int*)g,
                                   (__attribute__((address_space(3))) unsigned int*)l, 16, 0, 0);
}

// ---- prep: Wih1, Wih2 f32 -> bf16 flat
__global__ __launch_bounds__(256) void kconv2(const float* __restrict__ a0,
    const float* __restrict__ a1, unsigned short* __restrict__ d0,
    unsigned short* __restrict__ d1){
  int i = blockIdx.x*256 + threadIdx.x;   // grid 3072*256 = 786432
  d0[i] = f2bf(a0[i]); d1[i] = f2bf(a1[i]);
}

// ---- prep: Whh -> fragment-permuted bf16 so kgru weight loads are coalesced.
// dst i = (((wblk*3+g)*16+ks)*64+lane)*8+e ; wblk=cb*8+w owns cols wblk*16..+15
__global__ __launch_bounds__(256) void kwperm(const float* __restrict__ wsrc,
    unsigned short* __restrict__ o){
  int i = blockIdx.x*256 + threadIdx.x;   // grid 3072
  int e = i & 7, lane = (i >> 3) & 63, ks = (i >> 9) & 15, rem = i >> 13;
  int g = rem % 3, wblk = rem / 3;
  int gcol = wblk*16 + (lane & 15);
  int k = ks*32 + (lane >> 4)*8 + e;
  o[i] = f2bf(wsrc[(size_t)(g*512 + gcol)*512 + k]);
}

// ---- prep: Wih0 pad 161->192 to bf16; fc_W transpose to [512][64] f32
__global__ __launch_bounds__(256) void kmisc(const float* __restrict__ wih0,
    unsigned short* __restrict__ wih0p, const float* __restrict__ fcw,
    float* __restrict__ fcwt){
  int i = blockIdx.x*256 + threadIdx.x;  // grid 1152
  if (i < 1536*192){
    int n = i / 192, k = i - n*192;
    wih0p[i] = (k < 161) ? f2bf(wih0[n*161 + k]) : (unsigned short)0;
  }
  if (i < 512*64){
    int k = i >> 6, v = i & 63;
    fcwt[i] = fcw[v*512 + k];
  }
}

// ---- prep: build x0 [32768][192] bf16 in (t,b) order: m = t*256 + b
__global__ __launch_bounds__(192) void kx0(const float* __restrict__ latent,
    const float* __restrict__ enth, const int* __restrict__ inp,
    const float* __restrict__ emb, unsigned short* __restrict__ x0){
  int c = threadIdx.x;
  #pragma unroll
  for (int mr = 0; mr < 4; ++mr){
    int m = blockIdx.x*4 + mr;       // grid 8192
    int b = m & 255, t = m >> 8;
    float v;
    if (c < 128) v = latent[b*128 + c];
    else if (c < 160){
      int tok = (t == 0) ? 0 : inp[b*128 + t - 1];
      v = emb[tok*32 + (c - 128)];
    }
    else if (c == 160) v = enth[b];
    else v = 0.f;
    x0[(size_t)m*192 + c] = f2bf(v);
  }
}

// ---- bf16 MFMA GEMM (row-order-blind): C[m][n] = A[m][K] @ Bt[n][K]^T + bias[n]
__global__ __launch_bounds__(256) void kgemm(const unsigned short* __restrict__ A,
    const unsigned short* __restrict__ Bt, const float* __restrict__ bias,
    unsigned short* __restrict__ C, int K){
  __shared__ __align__(16) unsigned short As[128*32];
  __shared__ __align__(16) unsigned short Bs[128*32];
  const int m0 = blockIdx.y*128, n0 = blockIdx.x*128;
  const int wv = threadIdx.x >> 6, lane = threadIdx.x & 63;
  const int woffM = (wv >> 1)*64, woffN = (wv & 1)*64;
  f32x4 acc[4][4] = {};
  for (int k0 = 0; k0 < K; k0 += 32){
    __syncthreads();
    #pragma unroll
    for (int i = 0; i < 4; ++i){
      int e = wv*4 + i;
      int ee = e & 7;
      int row = ee*16 + (lane >> 2);
      if (e < 8) gl_lds16(A  + (size_t)(m0+row)*K + k0 + (lane & 3)*8, (void*)&As[ee*512]);
      else       gl_lds16(Bt + (size_t)(n0+row)*K + k0 + (lane & 3)*8, (void*)&Bs[ee*512]);
    }
    __syncthreads();
    bf16x8 af[4], bf_[4];
    #pragma unroll
    for (int mt = 0; mt < 4; ++mt)
      af[mt] = *(const bf16x8*)&As[(woffM + mt*16 + (lane & 15))*32 + (lane >> 4)*8];
    #pragma unroll
    for (int nt = 0; nt < 4; ++nt)
      bf_[nt] = *(const bf16x8*)&Bs[(woffN + nt*16 + (lane & 15))*32 + (lane >> 4)*8];
    #pragma unroll
    for (int mt = 0; mt < 4; ++mt)
      #pragma unroll
      for (int nt = 0; nt < 4; ++nt)
        acc[mt][nt] = __builtin_amdgcn_mfma_f32_16x16x32_bf16(af[mt], bf_[nt], acc[mt][nt], 0, 0, 0);
  }
  const int col = lane & 15, lq = lane >> 4;
  #pragma unroll
  for (int nt = 0; nt < 4; ++nt){
    float bv = bias[n0 + woffN + nt*16 + col];
    #pragma unroll
    for (int mt = 0; mt < 4; ++mt)
      #pragma unroll
      for (int r = 0; r < 4; ++r){
        int grow = m0 + woffM + mt*16 + lq*4 + r;
        int gcol = n0 + woffN + nt*16 + col;
        C[(size_t)grow*G3 + gcol] = f2bf(acc[mt][nt][r] + bv);
      }
  }
}

// ---- GRU layer: 64 blocks = 16 rowgroups(16 rows) x 4 colblocks(128 cols x 3 gates).
// 512 threads / 8 waves. Whh slice resident (192 regs/lane, unified VGPR+AGPR file).
// h exchange via proven MALL protocol (atomics only; sc0/sc1 asm failed R5/R9).
// R12 chain fixes: (1) gi loaded as raw ushort BEFORE poll, converted after the
// staging barrier -> gi HBM latency overlaps the poll instead of preceding it;
// (2) only wave 0 polls the 32 flags (8x less atomic poll traffic), other waves
// released by barrier. hist[t][B][512] = publish target AND next-GEMM A matrix.
template<int STORE_F>
__global__ __launch_bounds__(512, 2) void kgru(
    const unsigned short* __restrict__ Wp, const float* __restrict__ bhh,
    const unsigned short* __restrict__ gi,
    unsigned short* __restrict__ hist, float* __restrict__ x2f,
    int* __restrict__ flags){
  const int bid = blockIdx.x;
  const int rg = bid & 15, cb = bid >> 4;
  const int b0 = rg*16;
  const int tid = threadIdx.x;
  const int w = tid >> 6, lane = tid & 63;
  const int c = lane & 15, lq = lane >> 4;
  const int gcol = cb*128 + w*16 + c;
  __shared__ __align__(16) unsigned short hs[2][16*512];   // 32KB staging (dbuf)
  __shared__ __align__(16) unsigned short hpub[8][256];    // 4KB bf16 publish shuffle
  __shared__ __align__(16) float hpf[8][256];              // 8KB f32 shuffle (final layer)

  // resident Whh fragments (coalesced; pre-permuted): 192 regs/lane
  const unsigned short* wbase = Wp + (size_t)(cb*8 + w)*24576 + lane*8;
  bf16x8 wf[3][16];
  #pragma unroll
  for (int g = 0; g < 3; ++g)
    #pragma unroll
    for (int ks = 0; ks < 16; ++ks)
      wf[g][ks] = *(const bf16x8*)(wbase + g*8192 + ks*512);
  float bias[3];
  #pragma unroll
  for (int g = 0; g < 3; ++g) bias[g] = bhh[g*512 + gcol];
  float h_old[4] = {0.f, 0.f, 0.f, 0.f};

  unsigned long long* hist8 = (unsigned long long*)hist;
  int* myf = flags + rg*32;                      // 32 per-wave slots (cb*8+w)
  const unsigned short* gp = gi + (size_t)(b0 + lq*4)*G3 + gcol;

  #pragma unroll 1
  for (int t = 0; t < TT; ++t){
    // A: issue gi loads RAW (no conversion -> no waitcnt before the poll)
    unsigned short gvr[4][3];
    #pragma unroll
    for (int r = 0; r < 4; ++r){
      const unsigned short* p = gp + (size_t)r*G3;
      gvr[r][0] = p[0]; gvr[r][1] = p[512]; gvr[r][2] = p[1024];
    }
    gp += (size_t)256*G3;
    // B: wave0-only poll of the 32 per-wave flags
    if (t > 0 && w == 0){
      while (true){
        int f = __hip_atomic_load(myf + (lane & 31), __ATOMIC_RELAXED, __HIP_MEMORY_SCOPE_AGENT);
        if (__all(f >= t)) break;
        __builtin_amdgcn_s_sleep(1);
      }
    }
    __syncthreads();                               // release: h_{t-1} fully published
    if (t > 0){
      // C: pull 16KB of h_{t-1} (2048 qwords, 4/thread) -> swizzled LDS
      const unsigned long long* src8 = hist8 + ((size_t)(t - 1)*256 + b0)*128;
      unsigned long long pv[4];
      #pragma unroll
      for (int j = 0; j < 4; ++j)
        pv[j] = __hip_atomic_load(src8 + tid + j*512, __ATOMIC_RELAXED, __HIP_MEMORY_SCOPE_AGENT);
      char* hsw = (char*)hs[t & 1];
      #pragma unroll
      for (int j = 0; j < 4; ++j){
        int idx = tid + j*512;
        int row = idx >> 7, q = idx & 127;
        *(unsigned long long*)(hsw + row*1024 + (((q >> 1) ^ (row & 7)) << 4)
                               + ((q & 1) << 3)) = pv[j];
      }
    }
    __syncthreads();                               // staging barrier
    // D: NOW convert gi (loads long since landed; latency overlapped poll)
    f32x4 acc[3]; f32x4 gin;
    #pragma unroll
    for (int r = 0; r < 4; ++r){
      acc[0][r] = bf2f(gvr[r][0]) + bias[0];
      acc[1][r] = bf2f(gvr[r][1]) + bias[1];
      acc[2][r] = bias[2];
      gin[r]    = bf2f(gvr[r][2]);
    }
    if (t > 0){
      const char* hsr = (const char*)hs[t & 1];
      #pragma unroll
      for (int ks = 0; ks < 16; ++ks){
        bf16x8 af = *(const bf16x8*)(hsr + c*1024 + (((ks*4 + lq) ^ (c & 7)) << 4));
        acc[0] = __builtin_amdgcn_mfma_f32_16x16x32_bf16(af, wf[0][ks], acc[0], 0, 0, 0);
        acc[1] = __builtin_amdgcn_mfma_f32_16x16x32_bf16(af, wf[1][ks], acc[1], 0, 0, 0);
        acc[2] = __builtin_amdgcn_mfma_f32_16x16x32_bf16(af, wf[2][ks], acc[2], 0, 0, 0);
      }
    }
    // E: gates (fully in-lane)
    unsigned short hv[4]; float hf[4];
    #pragma unroll
    for (int r = 0; r < 4; ++r){
      float rr = 1.f/(1.f + __expf(-acc[0][r]));
      float zz = 1.f/(1.f + __expf(-acc[1][r]));
      float np = gin[r] + rr*acc[2][r];
      float ee = __expf(2.f*np);
      float nn = 1.f - 2.f/(ee + 1.f);
      float hn = (1.f - zz)*nn + zz*h_old[r];
      h_old[r] = hn; hf[r] = hn; hv[r] = f2bf(hn);
    }
    // F: wave-local publish shuffle (16 rows x 16 cols per wave)
    #pragma unroll
    for (int r = 0; r < 4; ++r)
      hpub[w][(lq*4 + r)*16 + c] = hv[r];
    if (STORE_F){
      #pragma unroll
      for (int r = 0; r < 4; ++r)
        hpf[w][(lq*4 + r)*16 + c] = hf[r];
    }
    __builtin_amdgcn_sched_barrier(0);
    // G: 1 qword/lane coalesced atomic publish; per-wave drain; per-wave flag
    unsigned long long pub = *(const unsigned long long*)&hpub[w][(lane >> 2)*16 + (lane & 3)*4];
    unsigned long long* dst8 = hist8 + ((size_t)t*256 + b0)*128;
    __hip_atomic_store(dst8 + (lane >> 2)*128 + cb*32 + w*4 + (lane & 3), pub,
                       __ATOMIC_RELAXED, __HIP_MEMORY_SCOPE_AGENT);
    asm volatile("s_waitcnt vmcnt(0)" ::: "memory");   // this wave's h at MALL
    if (lane == 0)
      __hip_atomic_store(myf + (cb*8 + w), t + 1, __ATOMIC_RELAXED, __HIP_MEMORY_SCOPE_AGENT);
    __builtin_amdgcn_sched_barrier(0);                 // f32 stream strictly after flag
    if (STORE_F){
      const float* pf = &hpf[w][(lane >> 2)*16 + (lane & 3)*4];
      unsigned long long f0 = ((const unsigned long long*)pf)[0];
      unsigned long long f1 = ((const unsigned long long*)pf)[1];
      unsigned long long* xd = (unsigned long long*)x2f
          + ((size_t)t*256 + b0 + (lane >> 2))*256 + cb*64 + w*8 + (lane & 3)*2;
      xd[0] = f0; xd[1] = f1;
    }
  }
}

// ---- final FC in f32: logits[b][t][64] = x[(t,b)][512] @ fcwt + fc_b
__global__ __launch_bounds__(256) void kfc(const float* __restrict__ x,
    const float* __restrict__ wt, const float* __restrict__ fcb, float* __restrict__ out){
  __shared__ __align__(16) float xs[16*512];
  const int m0 = blockIdx.x*16;   // grid 2048; 16 rows share t (16 | 256)
  for (int c = threadIdx.x; c < 2048; c += 256){
    int row = c >> 7, o = c & 127;
    *(f32x4*)&xs[row*512 + o*4] = *(const f32x4*)(x + (size_t)(m0+row)*512 + o*4);
  }
  __syncthreads();
  const int colv = threadIdx.x & 63, rq = threadIdx.x >> 6;
  float a0 = 0.f, a1 = 0.f, a2 = 0.f, a3 = 0.f;
  const float* x0p = xs + (rq*4 + 0)*512;
  const float* x1p = xs + (rq*4 + 1)*512;
  const float* x2p = xs + (rq*4 + 2)*512;
  const float* x3p = xs + (rq*4 + 3)*512;
  #pragma unroll 8
  for (int k = 0; k < 512; ++k){
    float w = wt[k*64 + colv];
    a0 += w * x0p[k]; a1 += w * x1p[k]; a2 += w * x2p[k]; a3 += w * x3p[k];
  }
  float bv = fcb[colv];
  float av[4] = {a0, a1, a2, a3};
  #pragma unroll
  for (int j = 0; j < 4; ++j){
    int m = m0 + rq*4 + j;
    int b = m & 255, t = m >> 8;               // (t,b) -> [b][t][64] output
    out[((size_t)b*128 + t)*64 + colv] = av[j] + bv;
  }
}

extern "C" void kernel_launch(void* const* d_in, const int* in_sizes, int n_in,
                              void* d_out, int out_size, void* d_ws, size_t ws_size,
                              hipStream_t stream){
  const float* latent = (const float*)d_in[0];
  const float* enth   = (const float*)d_in[1];
  const int*   inp    = (const int*)d_in[2];
  const float* emb    = (const float*)d_in[3];
  const float* Wih0   = (const float*)d_in[4];
  const float* Whh0   = (const float*)d_in[5];
  const float* bih0   = (const float*)d_in[6];
  const float* bhh0   = (const float*)d_in[7];
  const float* Wih1   = (const float*)d_in[8];
  const float* Whh1   = (const float*)d_in[9];
  const float* bih1   = (const float*)d_in[10];
  const float* bhh1   = (const float*)d_in[11];
  const float* Wih2   = (const float*)d_in[12];
  const float* Whh2   = (const float*)d_in[13];
  const float* bih2   = (const float*)d_in[14];
  const float* bhh2   = (const float*)d_in[15];
  const float* fcW    = (const float*)d_in[16];
  const float* fcb    = (const float*)d_in[17];

  char* ws = (char*)d_ws;
  constexpr size_t OFF_HIST = 4096;                                  // flags at 0 (2KB)
  constexpr size_t OFF_X0   = OFF_HIST + (size_t)32768*512*2;        // 32MB hist
  constexpr size_t OFF_X2F  = OFF_X0   + (size_t)32768*192*2;
  constexpr size_t OFF_WHP  = OFF_X2F  + (size_t)32768*512*4;
  constexpr size_t OFF_WIH0 = OFF_WHP  + (size_t)3*1536*512*2;
  constexpr size_t OFF_WIH1 = OFF_WIH0 + (size_t)1536*192*2;
  constexpr size_t OFF_WIH2 = OFF_WIH1 + (size_t)1536*512*2;
  constexpr size_t OFF_FCWT = OFF_WIH2 + (size_t)1536*512*2;
  constexpr size_t OFF_GI   = OFF_FCWT + (size_t)512*64*4;

  int* flags            = (int*)ws;
  unsigned short* hist  = (unsigned short*)(ws + OFF_HIST);
  unsigned short* x0    = (unsigned short*)(ws + OFF_X0);
  float* x2f            = (float*)(ws + OFF_X2F);
  unsigned short* whp0  = (unsigned short*)(ws + OFF_WHP);
  unsigned short* whp1  = whp0 + (size_t)1536*512;
  unsigned short* whp2  = whp1 + (size_t)1536*512;
  unsigned short* wih0p = (unsigned short*)(ws + OFF_WIH0);
  unsigned short* wih1b = (unsigned short*)(ws + OFF_WIH1);
  unsigned short* wih2b = (unsigned short*)(ws + OFF_WIH2);
  float* fcwt           = (float*)(ws + OFF_FCWT);
  unsigned short* gi    = (unsigned short*)(ws + OFF_GI);

  kconv2<<<3072, 256, 0, stream>>>(Wih1, Wih2, wih1b, wih2b);
  kwperm<<<3072, 256, 0, stream>>>(Whh0, whp0);
  kwperm<<<3072, 256, 0, stream>>>(Whh1, whp1);
  kwperm<<<3072, 256, 0, stream>>>(Whh2, whp2);
  kmisc <<<1152, 256, 0, stream>>>(Wih0, wih0p, fcW, fcwt);
  kx0   <<<8192, 192, 0, stream>>>(latent, enth, inp, emb, x0);

  kgemm<<<dim3(12,256), 256, 0, stream>>>(x0, wih0p, bih0, gi, 192);
  (void)hipMemsetAsync(flags, 0, 2048, stream);
  kgru<0><<<64, 512, 0, stream>>>(whp0, bhh0, gi, hist, x2f, flags);
  kgemm<<<dim3(12,256), 256, 0, stream>>>(hist, wih1b, bih1, gi, 512);
  (void)hipMemsetAsync(flags, 0, 2048, stream);
  kgru<0><<<64, 512, 0, stream>>>(whp1, bhh1, gi, hist, x2f, flags);
  kgemm<<<dim3(12,256), 256, 0, stream>>>(hist, wih2b, bih2, gi, 512);
  (void)hipMemsetAsync(flags, 0, 2048, stream);
  kgru<1><<<64, 512, 0, stream>>>(whp2, bhh2, gi, hist, x2f, flags);
  kfc  <<<2048, 256, 0, stream>>>(x2f, fcwt, fcb, (float*)d_out);
}